// Round 7
// baseline (407.869 us; speedup 1.0000x reference)
//
#include <hip/hip_runtime.h>
#include <math.h>

#define HH 512
#define WW 512
#define HW (HH * WW)
#define PW 514                    // padded width/height
#define PPIX (PW * PW)            // pixels per padded plane-set

typedef short bf16x8 __attribute__((ext_vector_type(8)));
typedef float f32x4 __attribute__((ext_vector_type(4)));

__device__ __forceinline__ ushort f2bf(float f) {
    union { float f; uint u; } c; c.f = f;
    uint u = c.u;
    return (ushort)((u + 0x7fffu + ((u >> 16) & 1u)) >> 16);
}

__device__ __forceinline__ uint cvtpk(float a, float b) {
    uint r;
    asm("v_cvt_pk_bf16_f32 %0, %1, %2" : "=v"(r) : "v"(a), "v"(b));
    return r;
}

// ---------------- kernel 1: styles = ws @ (aw.T / sqrt(512)) + ab ----------------
__global__ void k_styles(const float* __restrict__ wsv, const float* __restrict__ aw,
                         const float* __restrict__ ab, float* __restrict__ styles) {
    int bid = blockIdx.x;
    int b = bid >> 6, ci = bid & 63;
    int l = threadIdx.x;
    const float* wrow = wsv + b * 512;
    const float* arow = aw + ci * 512;
    float s = 0.f;
    #pragma unroll
    for (int j = 0; j < 8; ++j)
        s += wrow[l + 64 * j] * arow[l + 64 * j];
    #pragma unroll
    for (int off = 32; off; off >>= 1)
        s += __shfl_xor(s, off, 64);
    if (l == 0)
        styles[b * 64 + ci] = s * 0.044194173824159216f + ab[ci];
}

// ------------- kernel 2: modulate + demodulate -> bf16 [b][k(9)][co][ci] -------------
__global__ void k_wmod(const float* __restrict__ cw, const float* __restrict__ styles,
                       ushort* __restrict__ wb) {
    int b = blockIdx.x >> 6, co = blockIdx.x & 63;
    int ci = threadIdx.x;
    float st = styles[b * 64 + ci];
    const float* wp = cw + (co * 64 + ci) * 9;
    float wv[9];
    float ss = 0.f;
    #pragma unroll
    for (int k = 0; k < 9; ++k) { wv[k] = wp[k] * st; ss += wv[k] * wv[k]; }
    #pragma unroll
    for (int off = 32; off; off >>= 1)
        ss += __shfl_xor(ss, off, 64);
    float dm = 1.0f / sqrtf(ss + 1e-8f);
    #pragma unroll
    for (int k = 0; k < 9; ++k)
        wb[((size_t)(b * 9 + k) * 64 + co) * 64 + ci] = f2bf(wv[k] * dm);
}

// ------------- kernel 2b: zero the pad border of xp -------------
__global__ void k_zeropad(ushort* __restrict__ xp) {
    int id = blockIdx.x * 256 + threadIdx.x;
    if (id >= 4 * 2052) return;
    int b = id / 2052, r = id % 2052;
    int gyp, gxp;
    if (r < 514)       { gyp = 0;        gxp = r; }
    else if (r < 1028) { gyp = 513;      gxp = r - 514; }
    else if (r < 1540) { gyp = r - 1027; gxp = 0; }
    else               { gyp = r - 1539; gxp = 513; }
    ushort* p = xp + (((size_t)b * PW + gyp) * PW + gxp) * 64;
    uint4 z = make_uint4(0, 0, 0, 0);
    #pragma unroll
    for (int i = 0; i < 8; ++i) *(uint4*)(p + i * 8) = z;
}

// ------------- kernel 2c: x fp32 [b][ci][H][W] -> xp bf16 [b][gy+1][gx+1][ci] -------------
__global__ __launch_bounds__(256) void k_xpose(
    const float* __restrict__ x, ushort* __restrict__ xp) {
    __shared__ ushort lt[128 * 68];
    const int t = threadIdx.x;
    const int bid = blockIdx.x;          // 4 b x 512 gy x 4 gxt
    const int gxt = bid & 3;
    const int gy  = (bid >> 2) & 511;
    const int b   = bid >> 11;

    const float* xb = x + (size_t)b * 64 * HW + (size_t)gy * WW + gxt * 128;
    const int ci0 = 8 * (t >> 5);
    const int gxc = t & 31;

    f32x4 v[8];
    #pragma unroll
    for (int j = 0; j < 8; ++j)
        v[j] = *(const f32x4*)(xb + (size_t)(ci0 + j) * HW + gxc * 4);

    #pragma unroll
    for (int p = 0; p < 4; ++p) {
        int px = gxc * 4 + p;
        int rowp = ((px & 3) * 32 + (px >> 2)) * 68;
        #pragma unroll
        for (int cg = 0; cg < 2; ++cg) {
            uint lo = cvtpk(v[4 * cg + 0][p], v[4 * cg + 1][p]);
            uint hi = cvtpk(v[4 * cg + 2][p], v[4 * cg + 3][p]);
            *(uint2*)&lt[rowp + ci0 + 4 * cg] = make_uint2(lo, hi);
        }
    }
    __syncthreads();

    const int px = t >> 1, half = t & 1;
    const int rowp = ((px & 3) * 32 + (px >> 2)) * 68 + half * 32;
    uint4 o0 = *(uint4*)&lt[rowp + 0];
    uint4 o1 = *(uint4*)&lt[rowp + 8];
    uint4 o2 = *(uint4*)&lt[rowp + 16];
    uint4 o3 = *(uint4*)&lt[rowp + 24];
    ushort* dst = xp + (((size_t)b * PW + (gy + 1)) * PW + (gxt * 128 + px + 1)) * 64
                     + half * 32;
    *(uint4*)(dst + 0)  = o0;
    *(uint4*)(dst + 8)  = o1;
    *(uint4*)(dst + 16) = o2;
    *(uint4*)(dst + 24) = o3;
}

// ------------- kernel 3: MFMA implicit-GEMM conv + epilogue -------------
// Block: 512 threads (8 waves). Output tile: 64 co x (8 rows x 32 cols).
// Wave w owns output row w (n-tiles 2w, 2w+1). acc = 32 VGPR/thread.
// Staging: 43 x global_load_lds (1KB, bf16, contiguous) into
// tile[row 10][lcol 34][ci 64]; read swizzle realized by pre-swizzled
// SOURCE address (content at ci-slot g is global group g ^ (lcol&7)).
// LDS 44KB -> 3 blocks/CU -> 24 waves/CU: cross-block phase overlap.
__global__ __launch_bounds__(512) void k_conv(
    const ushort* __restrict__ xp,    // [4][514][514][64] bf16 padded
    const ushort* __restrict__ wb,    // [4][9][64][64] bf16
    const float* __restrict__ noise,  // [4][1][512][512]
    const float* __restrict__ bias,   // [64]
    float* __restrict__ out) {        // [4][64][512][512] fp32
    __shared__ ushort tile[2752 * 8];   // 44032 B (2720 used + slack)

    const int t = threadIdx.x;
    const int b = blockIdx.y;
    const int colb = blockIdx.x & 15;
    const int rowb = blockIdx.x >> 4;
    const int tx = colb * 32, ty = rowb * 8;
    const int w = t >> 6;
    const int lane = t & 63;

    const ushort* xpb = xp + (size_t)b * PPIX * 64;

    // ---- staging: 43 x 1KB global_load_lds, 5-6 per wave ----
    for (int j = w; j < 43; j += 8) {
        int c = j * 64 + lane;
        int c2 = c < 2719 ? c : 2719;      // clamp garbage lanes in-bounds
        int cig = c2 & 7;
        int pxl = c2 >> 3;
        int row = pxl / 34;
        int lcol = pxl - row * 34;
        int gsrc = cig ^ (lcol & 7);       // pre-swizzled source ci-group
        const ushort* src = xpb + ((size_t)(ty + row) * PW + (tx + lcol)) * 64 + gsrc * 8;
        __builtin_amdgcn_global_load_lds(
            (const __attribute__((address_space(1))) unsigned int*)src,
            (__attribute__((address_space(3))) unsigned int*)&tile[j * 512],
            16, 0, 0);
    }
    asm volatile("s_waitcnt vmcnt(0)" ::: "memory");
    __syncthreads();

    // ---- compute ----
    const int lr = lane & 15;
    const int lq = lane >> 4;

    int bidx[2][3];
    #pragma unroll
    for (int i = 0; i < 2; ++i) {
        int nt = 2 * w + i;
        int prow = nt >> 1;                // = w
        int c = (nt & 1) * 16 + lr;
        #pragma unroll
        for (int dx = 0; dx < 3; ++dx) {
            int lcol = c + dx;
            bidx[i][dx] = (prow * 34 + lcol) * 64 + ((lq * 8) ^ ((lcol & 7) << 3));
        }
    }

    const ushort* wbb = wb + (size_t)b * 9 * 4096 + lr * 64 + lq * 8;

    f32x4 acc[4][2];
    #pragma unroll
    for (int m = 0; m < 4; ++m)
        #pragma unroll
        for (int i = 0; i < 2; ++i) acc[m][i] = (f32x4){0.f, 0.f, 0.f, 0.f};

    #pragma unroll
    for (int dy = 0; dy < 3; ++dy) {
        #pragma unroll
        for (int dx = 0; dx < 3; ++dx) {
            #pragma unroll
            for (int kb = 0; kb < 2; ++kb) {
                const int off = dy * 3 + dx;
                bf16x8 afr[4], bfr[2];
                #pragma unroll
                for (int m = 0; m < 4; ++m)
                    afr[m] = *(const bf16x8*)(wbb + off * 4096 + m * 1024 + kb * 32);
                #pragma unroll
                for (int i = 0; i < 2; ++i) {
                    int idx = (bidx[i][dx] + dy * (34 * 64)) ^ (kb << 5);
                    bfr[i] = *(const bf16x8*)&tile[idx];
                }
                #pragma unroll
                for (int m = 0; m < 4; ++m)
                    #pragma unroll
                    for (int i = 0; i < 2; ++i)
                        acc[m][i] = __builtin_amdgcn_mfma_f32_16x16x32_bf16(
                            afr[m], bfr[i], acc[m][i], 0, 0, 0);
            }
        }
    }

    // ---- epilogue: +noise, +bias, lrelu*sqrt2, clamp, store ----
    const float* nz = noise + (size_t)b * HW;
    float nv[2];
    int gyv[2], gxv[2];
    #pragma unroll
    for (int i = 0; i < 2; ++i) {
        gyv[i] = ty + w;
        gxv[i] = tx + i * 16 + lr;
        nv[i] = nz[gyv[i] * WW + gxv[i]];
    }
    #pragma unroll
    for (int m = 0; m < 4; ++m) {
        f32x4 bv = *(const f32x4*)&bias[m * 16 + lq * 4];
        #pragma unroll
        for (int i = 0; i < 2; ++i) {
            #pragma unroll
            for (int rg2 = 0; rg2 < 4; ++rg2) {
                int co = m * 16 + lq * 4 + rg2;
                float y = acc[m][i][rg2] + nv[i] + bv[rg2];
                y = (y >= 0.f ? y : 0.2f * y) * 1.41421356237f;
                y = fminf(fmaxf(y, -256.f), 256.f);
                out[((size_t)(b * 64 + co) * HH + gyv[i]) * WW + gxv[i]] = y;
            }
        }
    }
}

extern "C" void kernel_launch(void* const* d_in, const int* in_sizes, int n_in,
                              void* d_out, int out_size, void* d_ws, size_t ws_size,
                              hipStream_t stream) {
    const float* x     = (const float*)d_in[0];
    const float* wsv   = (const float*)d_in[1];
    const float* noise = (const float*)d_in[2];
    const float* aw    = (const float*)d_in[3];
    const float* ab    = (const float*)d_in[4];
    const float* cw    = (const float*)d_in[5];
    const float* bias  = (const float*)d_in[6];
    float* out = (float*)d_out;

    float*  styles = (float*)d_ws;                          // 1 KB
    ushort* wb16   = (ushort*)((char*)d_ws + 1024);         // 294912 B
    ushort* xpad   = (ushort*)((char*)d_ws + (1 << 20));    // 135.3 MB

    k_styles<<<256, 64, 0, stream>>>(wsv, aw, ab, styles);
    k_wmod<<<256, 64, 0, stream>>>(cw, styles, wb16);
    k_zeropad<<<33, 256, 0, stream>>>(xpad);
    k_xpose<<<8192, 256, 0, stream>>>(x, xpad);
    dim3 grid(1024, 4);
    k_conv<<<grid, 512, 0, stream>>>(xpad, wb16, noise, bias, out);
}

// Round 8
// 267.930 us; speedup vs baseline: 1.5223x; 1.5223x over previous
//
#include <hip/hip_runtime.h>
#include <math.h>

#define HH 512
#define WW 512
#define HW (HH * WW)
#define PW 514                    // padded width/height
#define PPIX (PW * PW)

typedef short bf16x8 __attribute__((ext_vector_type(8)));
typedef float f32x4 __attribute__((ext_vector_type(4)));

__device__ __forceinline__ ushort f2bf(float f) {
    union { float f; uint u; } c; c.f = f;
    uint u = c.u;
    return (ushort)((u + 0x7fffu + ((u >> 16) & 1u)) >> 16);
}

__device__ __forceinline__ uint cvtpk(float a, float b) {
    uint r;
    asm("v_cvt_pk_bf16_f32 %0, %1, %2" : "=v"(r) : "v"(a), "v"(b));
    return r;
}

// ---------------- kernel 1: styles ----------------
__global__ void k_styles(const float* __restrict__ wsv, const float* __restrict__ aw,
                         const float* __restrict__ ab, float* __restrict__ styles) {
    int bid = blockIdx.x;
    int b = bid >> 6, ci = bid & 63;
    int l = threadIdx.x;
    const float* wrow = wsv + b * 512;
    const float* arow = aw + ci * 512;
    float s = 0.f;
    #pragma unroll
    for (int j = 0; j < 8; ++j)
        s += wrow[l + 64 * j] * arow[l + 64 * j];
    #pragma unroll
    for (int off = 32; off; off >>= 1)
        s += __shfl_xor(s, off, 64);
    if (l == 0)
        styles[b * 64 + ci] = s * 0.044194173824159216f + ab[ci];
}

// ------------- kernel 2: modulate+demodulate -> bf16 [b][co][off 9][ci 64] -------------
// ci-group (ci>>3) stored XORed with (co&7): conflict-free A ds_reads after a
// purely LINEAR global_load_lds stage (swizzle baked at write time).
__global__ void k_wmod(const float* __restrict__ cw, const float* __restrict__ styles,
                       ushort* __restrict__ wb) {
    int b = blockIdx.x >> 6, co = blockIdx.x & 63;
    int ci = threadIdx.x;
    float st = styles[b * 64 + ci];
    const float* wp = cw + (co * 64 + ci) * 9;
    float wv[9];
    float ss = 0.f;
    #pragma unroll
    for (int k = 0; k < 9; ++k) { wv[k] = wp[k] * st; ss += wv[k] * wv[k]; }
    #pragma unroll
    for (int off = 32; off; off >>= 1)
        ss += __shfl_xor(ss, off, 64);
    float dm = 1.0f / sqrtf(ss + 1e-8f);
    int cisw = ((((ci >> 3) ^ co) & 7) << 3) | (ci & 7);
    #pragma unroll
    for (int k = 0; k < 9; ++k)
        wb[((size_t)(b * 64 + co) * 9 + k) * 64 + cisw] = f2bf(wv[k] * dm);
}

// ------------- kernel 2b: zero the pad border of xp -------------
__global__ void k_zeropad(ushort* __restrict__ xp) {
    int id = blockIdx.x * 256 + threadIdx.x;
    if (id >= 4 * 2052) return;
    int b = id / 2052, r = id % 2052;
    int gyp, gxp;
    if (r < 514)       { gyp = 0;        gxp = r; }
    else if (r < 1028) { gyp = 513;      gxp = r - 514; }
    else if (r < 1540) { gyp = r - 1027; gxp = 0; }
    else               { gyp = r - 1539; gxp = 513; }
    ushort* p = xp + (((size_t)b * PW + gyp) * PW + gxp) * 64;
    uint4 z = make_uint4(0, 0, 0, 0);
    #pragma unroll
    for (int i = 0; i < 8; ++i) *(uint4*)(p + i * 8) = z;
}

// ------------- kernel 2c: x fp32 [b][ci][H][W] -> xp bf16 [b][gy+1][gx+1][ci] -------------
__global__ __launch_bounds__(256) void k_xpose(
    const float* __restrict__ x, ushort* __restrict__ xp) {
    __shared__ ushort lt[128 * 68];
    const int t = threadIdx.x;
    const int bid = blockIdx.x;          // 4 b x 512 gy x 4 gxt
    const int gxt = bid & 3;
    const int gy  = (bid >> 2) & 511;
    const int b   = bid >> 11;

    const float* xb = x + (size_t)b * 64 * HW + (size_t)gy * WW + gxt * 128;
    const int ci0 = 8 * (t >> 5);
    const int gxc = t & 31;

    f32x4 v[8];
    #pragma unroll
    for (int j = 0; j < 8; ++j)
        v[j] = *(const f32x4*)(xb + (size_t)(ci0 + j) * HW + gxc * 4);

    #pragma unroll
    for (int p = 0; p < 4; ++p) {
        int px = gxc * 4 + p;
        int rowp = ((px & 3) * 32 + (px >> 2)) * 68;
        #pragma unroll
        for (int cg = 0; cg < 2; ++cg) {
            uint lo = cvtpk(v[4 * cg + 0][p], v[4 * cg + 1][p]);
            uint hi = cvtpk(v[4 * cg + 2][p], v[4 * cg + 3][p]);
            *(uint2*)&lt[rowp + ci0 + 4 * cg] = make_uint2(lo, hi);
        }
    }
    __syncthreads();

    const int px = t >> 1, half = t & 1;
    const int rowp = ((px & 3) * 32 + (px >> 2)) * 68 + half * 32;
    uint4 o0 = *(uint4*)&lt[rowp + 0];
    uint4 o1 = *(uint4*)&lt[rowp + 8];
    uint4 o2 = *(uint4*)&lt[rowp + 16];
    uint4 o3 = *(uint4*)&lt[rowp + 24];
    ushort* dst = xp + (((size_t)b * PW + (gy + 1)) * PW + (gxt * 128 + px + 1)) * 64
                     + half * 32;
    *(uint4*)(dst + 0)  = o0;
    *(uint4*)(dst + 8)  = o1;
    *(uint4*)(dst + 16) = o2;
    *(uint4*)(dst + 24) = o3;
}

// ------------- kernel 3: MFMA implicit-GEMM conv + epilogue -------------
// Block: 256 threads (4 waves). Output: 32 co x (8 rows x 16 cols).
// LDS: B x-tile [row 10][lcol 18][ci 64] (23KB, source-pre-swizzled) +
//      A weights [co 32][off 9][ci 64] (36KB, swizzle baked by k_wmod,
//      staged as a pure linear copy).  Inner loop: ds_read + MFMA ONLY.
// Wave w: rows 2w, 2w+1 (i), both m-tiles (mt).  acc[2][2] f32x4.
__global__ __launch_bounds__(256) void k_conv(
    const ushort* __restrict__ xp,    // [4][514][514][64] bf16 padded
    const ushort* __restrict__ wb,    // [4][64co][9][64ci] bf16 (swizzled)
    const float* __restrict__ noise,  // [4][1][512][512]
    const float* __restrict__ bias,   // [64]
    float* __restrict__ out) {        // [4][64][512][512] fp32
    __shared__ ushort tileB[1472 * 8];   // 23552 B (1440 used)
    __shared__ ushort wlds[32 * 9 * 64]; // 36864 B

    const int t = threadIdx.x;
    const int b = blockIdx.y;
    const int coh = blockIdx.z;          // 0/1: co half
    const int colb = blockIdx.x & 31;
    const int rowb = blockIdx.x >> 5;
    const int tx = colb * 16, ty = rowb * 8;
    const int w = t >> 6;
    const int lane = t & 63;

    const ushort* xpb = xp + (size_t)b * PPIX * 64;
    const ushort* wA  = wb + (size_t)(b * 64 + coh * 32) * 576;

    // ---- stage A: 36 x 1KB linear copy ----
    for (int j = w; j < 36; j += 4) {
        const ushort* src = wA + j * 512 + lane * 8;
        __builtin_amdgcn_global_load_lds(
            (const __attribute__((address_space(1))) unsigned int*)src,
            (__attribute__((address_space(3))) unsigned int*)&wlds[j * 512],
            16, 0, 0);
    }
    // ---- stage B: 23 x 1KB, source-pre-swizzled ----
    for (int j = w; j < 23; j += 4) {
        int c = j * 64 + lane;
        int c2 = c < 1439 ? c : 1439;      // clamp tail in-bounds
        int cig = c2 & 7;
        int pxl = c2 >> 3;
        int row = pxl / 18;
        int lcol = pxl - row * 18;
        int gsrc = cig ^ (lcol & 7);
        const ushort* src = xpb + ((size_t)(ty + row) * PW + (tx + lcol)) * 64 + gsrc * 8;
        __builtin_amdgcn_global_load_lds(
            (const __attribute__((address_space(1))) unsigned int*)src,
            (__attribute__((address_space(3))) unsigned int*)&tileB[j * 512],
            16, 0, 0);
    }
    asm volatile("s_waitcnt vmcnt(0)" ::: "memory");
    __syncthreads();

    // ---- compute: LDS-only inner loop ----
    const int lr = lane & 15;
    const int lq = lane >> 4;

    int aidx[2][2];
    #pragma unroll
    for (int mt = 0; mt < 2; ++mt)
        #pragma unroll
        for (int kb = 0; kb < 2; ++kb)
            aidx[mt][kb] = (mt * 16 + lr) * 576 + ((((kb << 2) | lq) ^ (lr & 7)) << 3);

    int bidx[2][3];
    #pragma unroll
    for (int i = 0; i < 2; ++i)
        #pragma unroll
        for (int dx = 0; dx < 3; ++dx) {
            int lcol = lr + dx;
            bidx[i][dx] = ((2 * w + i) * 18 + lcol) * 64 + ((lq * 8) ^ ((lcol & 7) << 3));
        }

    f32x4 acc[2][2];
    #pragma unroll
    for (int mt = 0; mt < 2; ++mt)
        #pragma unroll
        for (int i = 0; i < 2; ++i) acc[mt][i] = (f32x4){0.f, 0.f, 0.f, 0.f};

    #pragma unroll
    for (int dy = 0; dy < 3; ++dy) {
        #pragma unroll
        for (int dx = 0; dx < 3; ++dx) {
            #pragma unroll
            for (int kb = 0; kb < 2; ++kb) {
                const int off = dy * 3 + dx;
                bf16x8 afr[2], bfr[2];
                #pragma unroll
                for (int mt = 0; mt < 2; ++mt)
                    afr[mt] = *(const bf16x8*)&wlds[aidx[mt][kb] + off * 64];
                #pragma unroll
                for (int i = 0; i < 2; ++i) {
                    int idx = (bidx[i][dx] + dy * (18 * 64)) ^ (kb << 5);
                    bfr[i] = *(const bf16x8*)&tileB[idx];
                }
                #pragma unroll
                for (int mt = 0; mt < 2; ++mt)
                    #pragma unroll
                    for (int i = 0; i < 2; ++i)
                        acc[mt][i] = __builtin_amdgcn_mfma_f32_16x16x32_bf16(
                            afr[mt], bfr[i], acc[mt][i], 0, 0, 0);
            }
        }
    }

    // ---- epilogue ----
    const float* nz = noise + (size_t)b * HW;
    float nv[2];
    int gyv[2];
    const int gx = tx + lr;
    #pragma unroll
    for (int i = 0; i < 2; ++i) {
        gyv[i] = ty + 2 * w + i;
        nv[i] = nz[gyv[i] * WW + gx];
    }
    #pragma unroll
    for (int mt = 0; mt < 2; ++mt) {
        f32x4 bv = *(const f32x4*)&bias[coh * 32 + mt * 16 + lq * 4];
        #pragma unroll
        for (int i = 0; i < 2; ++i) {
            #pragma unroll
            for (int rg2 = 0; rg2 < 4; ++rg2) {
                int co = coh * 32 + mt * 16 + lq * 4 + rg2;
                float y = acc[mt][i][rg2] + nv[i] + bv[rg2];
                y = (y >= 0.f ? y : 0.2f * y) * 1.41421356237f;
                y = fminf(fmaxf(y, -256.f), 256.f);
                out[((size_t)(b * 64 + co) * HH + gyv[i]) * WW + gx] = y;
            }
        }
    }
}

extern "C" void kernel_launch(void* const* d_in, const int* in_sizes, int n_in,
                              void* d_out, int out_size, void* d_ws, size_t ws_size,
                              hipStream_t stream) {
    const float* x     = (const float*)d_in[0];
    const float* wsv   = (const float*)d_in[1];
    const float* noise = (const float*)d_in[2];
    const float* aw    = (const float*)d_in[3];
    const float* ab    = (const float*)d_in[4];
    const float* cw    = (const float*)d_in[5];
    const float* bias  = (const float*)d_in[6];
    float* out = (float*)d_out;

    float*  styles = (float*)d_ws;                          // 1 KB
    ushort* wb16   = (ushort*)((char*)d_ws + 1024);         // 294912 B
    ushort* xpad   = (ushort*)((char*)d_ws + (1 << 20));    // 135.3 MB

    k_styles<<<256, 64, 0, stream>>>(wsv, aw, ab, styles);
    k_wmod<<<256, 64, 0, stream>>>(cw, styles, wb16);
    k_zeropad<<<33, 256, 0, stream>>>(xpad);
    k_xpose<<<8192, 256, 0, stream>>>(x, xpad);
    dim3 grid(2048, 4, 2);
    k_conv<<<grid, 256, 0, stream>>>(xpad, wb16, noise, bias, out);
}

// Round 9
// 267.453 us; speedup vs baseline: 1.5250x; 1.0018x over previous
//
#include <hip/hip_runtime.h>
#include <math.h>

#define HH 512
#define WW 512
#define HW (HH * WW)
#define PW 514                    // padded width/height
#define PPIX (PW * PW)

#define A_U    36864              // A region size in ushorts (64co*9*64ci)
#define B_STR  12032              // B buffer stride in ushorts (11520 + 512 pad for tail-clamp overflow)
#define LDS_BYTES ((A_U + 2 * B_STR) * 2)   // 121856 B <= 128KB (HK-proven)

typedef short bf16x8 __attribute__((ext_vector_type(8)));
typedef float f32x4 __attribute__((ext_vector_type(4)));

__device__ __forceinline__ ushort f2bf(float f) {
    union { float f; uint u; } c; c.f = f;
    uint u = c.u;
    return (ushort)((u + 0x7fffu + ((u >> 16) & 1u)) >> 16);
}

__device__ __forceinline__ uint cvtpk(float a, float b) {
    uint r;
    asm("v_cvt_pk_bf16_f32 %0, %1, %2" : "=v"(r) : "v"(a), "v"(b));
    return r;
}

// ---------------- kernel 1: styles ----------------
__global__ void k_styles(const float* __restrict__ wsv, const float* __restrict__ aw,
                         const float* __restrict__ ab, float* __restrict__ styles) {
    int bid = blockIdx.x;
    int b = bid >> 6, ci = bid & 63;
    int l = threadIdx.x;
    const float* wrow = wsv + b * 512;
    const float* arow = aw + ci * 512;
    float s = 0.f;
    #pragma unroll
    for (int j = 0; j < 8; ++j)
        s += wrow[l + 64 * j] * arow[l + 64 * j];
    #pragma unroll
    for (int off = 32; off; off >>= 1)
        s += __shfl_xor(s, off, 64);
    if (l == 0)
        styles[b * 64 + ci] = s * 0.044194173824159216f + ab[ci];
}

// ------------- kernel 2: modulate+demodulate -> bf16 [b][co][off 9][ci 64] -------------
// ci-group (ci>>3) stored XORed with (co&7): conflict-free A ds_reads after a
// purely LINEAR global_load_lds stage (swizzle baked at write time). (R8-proven)
__global__ void k_wmod(const float* __restrict__ cw, const float* __restrict__ styles,
                       ushort* __restrict__ wb) {
    int b = blockIdx.x >> 6, co = blockIdx.x & 63;
    int ci = threadIdx.x;
    float st = styles[b * 64 + ci];
    const float* wp = cw + (co * 64 + ci) * 9;
    float wv[9];
    float ss = 0.f;
    #pragma unroll
    for (int k = 0; k < 9; ++k) { wv[k] = wp[k] * st; ss += wv[k] * wv[k]; }
    #pragma unroll
    for (int off = 32; off; off >>= 1)
        ss += __shfl_xor(ss, off, 64);
    float dm = 1.0f / sqrtf(ss + 1e-8f);
    int cisw = ((((ci >> 3) ^ co) & 7) << 3) | (ci & 7);
    #pragma unroll
    for (int k = 0; k < 9; ++k)
        wb[((size_t)(b * 64 + co) * 9 + k) * 64 + cisw] = f2bf(wv[k] * dm);
}

// ------------- kernel 2b: zero the pad border of xp -------------
__global__ void k_zeropad(ushort* __restrict__ xp) {
    int id = blockIdx.x * 256 + threadIdx.x;
    if (id >= 4 * 2052) return;
    int b = id / 2052, r = id % 2052;
    int gyp, gxp;
    if (r < 514)       { gyp = 0;        gxp = r; }
    else if (r < 1028) { gyp = 513;      gxp = r - 514; }
    else if (r < 1540) { gyp = r - 1027; gxp = 0; }
    else               { gyp = r - 1539; gxp = 513; }
    ushort* p = xp + (((size_t)b * PW + gyp) * PW + gxp) * 64;
    uint4 z = make_uint4(0, 0, 0, 0);
    #pragma unroll
    for (int i = 0; i < 8; ++i) *(uint4*)(p + i * 8) = z;
}

// ------------- kernel 2c: x fp32 [b][ci][H][W] -> xp bf16 [b][gy+1][gx+1][ci] -------------
__global__ __launch_bounds__(256) void k_xpose(
    const float* __restrict__ x, ushort* __restrict__ xp) {
    __shared__ ushort lt[128 * 68];
    const int t = threadIdx.x;
    const int bid = blockIdx.x;          // 4 b x 512 gy x 4 gxt
    const int gxt = bid & 3;
    const int gy  = (bid >> 2) & 511;
    const int b   = bid >> 11;

    const float* xb = x + (size_t)b * 64 * HW + (size_t)gy * WW + gxt * 128;
    const int ci0 = 8 * (t >> 5);
    const int gxc = t & 31;

    f32x4 v[8];
    #pragma unroll
    for (int j = 0; j < 8; ++j)
        v[j] = *(const f32x4*)(xb + (size_t)(ci0 + j) * HW + gxc * 4);

    #pragma unroll
    for (int p = 0; p < 4; ++p) {
        int px = gxc * 4 + p;
        int rowp = ((px & 3) * 32 + (px >> 2)) * 68;
        #pragma unroll
        for (int cg = 0; cg < 2; ++cg) {
            uint lo = cvtpk(v[4 * cg + 0][p], v[4 * cg + 1][p]);
            uint hi = cvtpk(v[4 * cg + 2][p], v[4 * cg + 3][p]);
            *(uint2*)&lt[rowp + ci0 + 4 * cg] = make_uint2(lo, hi);
        }
    }
    __syncthreads();

    const int px = t >> 1, half = t & 1;
    const int rowp = ((px & 3) * 32 + (px >> 2)) * 68 + half * 32;
    uint4 o0 = *(uint4*)&lt[rowp + 0];
    uint4 o1 = *(uint4*)&lt[rowp + 8];
    uint4 o2 = *(uint4*)&lt[rowp + 16];
    uint4 o3 = *(uint4*)&lt[rowp + 24];
    ushort* dst = xp + (((size_t)b * PW + (gy + 1)) * PW + (gxt * 128 + px + 1)) * 64
                     + half * 32;
    *(uint4*)(dst + 0)  = o0;
    *(uint4*)(dst + 8)  = o1;
    *(uint4*)(dst + 16) = o2;
    *(uint4*)(dst + 24) = o3;
}

// ---- stage one B x-tile (10 rows x 18 cols x 64 ci) into buffer p ----
__device__ __forceinline__ void stage_b(ushort* lds, const ushort* __restrict__ xpb,
                                        int p, int tidx, int w, int lane) {
    const int ty = (tidx >> 5) * 8;
    const int tx = (tidx & 31) * 16;
    for (int j = w; j < 23; j += 4) {
        int c = j * 64 + lane;
        int c2 = c < 1439 ? c : 1439;       // tail clamp; dst overflow lands in pad
        int cig = c2 & 7;
        int pxl = c2 >> 3;
        int row = pxl / 18;
        int lcol = pxl - row * 18;
        int gsrc = cig ^ (lcol & 7);        // pre-swizzled source ci-group (R8-proven)
        const ushort* src = xpb + ((size_t)(ty + row) * PW + (tx + lcol)) * 64 + gsrc * 8;
        __builtin_amdgcn_global_load_lds(
            (const __attribute__((address_space(1))) unsigned int*)src,
            (__attribute__((address_space(3))) unsigned int*)&lds[A_U + p * B_STR + j * 512],
            16, 0, 0);
    }
}

// ------------- kernel 3: persistent-block MFMA conv, A-in-LDS, B double-buffered -------------
// 512 blocks (1/CU), 256 threads (4 waves). Each block: one b, stage A
// (64co x 576 = 72KB) once, then 16 px-tiles (8 rows x 16 cols) pipelined:
//   issue gload_lds(B next) -> compute cur (6 ds_read -> 8 MFMA per phase)
//   -> vmcnt(0)+barrier -> store cur.
__global__ __launch_bounds__(256) void k_conv(
    const ushort* __restrict__ xp,    // [4][514][514][64] bf16 padded
    const ushort* __restrict__ wb,    // [4][64co][9][64ci] bf16 (swizzle baked)
    const float* __restrict__ noise,  // [4][1][512][512]
    const float* __restrict__ bias,   // [64]
    float* __restrict__ out) {        // [4][64][512][512] fp32
    extern __shared__ __align__(16) ushort lds[];

    const int t = threadIdx.x;
    const int w = t >> 6;
    const int lane = t & 63;
    const int blk = blockIdx.x;
    const int b = blk >> 7;              // 128 blocks per batch image
    const int tile0 = (blk & 127) * 16;  // 16 tiles per block, row-major over 64x32 grid

    const ushort* xpb = xp + (size_t)b * PPIX * 64;
    const ushort* wA  = wb + (size_t)b * 64 * 576;

    // ---- stage A once: 72 x 1KB linear copy ----
    for (int j = w; j < 72; j += 4) {
        const ushort* src = wA + j * 512 + lane * 8;
        __builtin_amdgcn_global_load_lds(
            (const __attribute__((address_space(1))) unsigned int*)src,
            (__attribute__((address_space(3))) unsigned int*)&lds[j * 512],
            16, 0, 0);
    }
    // ---- stage B tile0 into buf0 ----
    stage_b(lds, xpb, 0, tile0, w, lane);
    asm volatile("s_waitcnt vmcnt(0)" ::: "memory");
    __syncthreads();

    const int lr = lane & 15;
    const int lq = lane >> 4;

    // A read offsets (R8-proven, 0 conflicts): [co][off][ci-swizzled]
    int aidx[4][2];
    #pragma unroll
    for (int m = 0; m < 4; ++m)
        #pragma unroll
        for (int kb = 0; kb < 2; ++kb)
            aidx[m][kb] = (m * 16 + lr) * 576 + ((((kb << 2) | lq) ^ (lr & 7)) << 3);

    // B read offsets (R8-proven): row = 2w+i, [row][lcol][ci-swizzled]
    int bidx[2][3];
    #pragma unroll
    for (int i = 0; i < 2; ++i)
        #pragma unroll
        for (int dx = 0; dx < 3; ++dx) {
            int lcol = lr + dx;
            bidx[i][dx] = ((2 * w + i) * 18 + lcol) * 64 + ((lq * 8) ^ ((lcol & 7) << 3));
        }

    f32x4 bv[4];
    #pragma unroll
    for (int m = 0; m < 4; ++m)
        bv[m] = *(const f32x4*)&bias[m * 16 + lq * 4];
    const float* nz = noise + (size_t)b * HW;

    int p = 0;
    for (int it = 0; it < 16; ++it) {
        const int tidx = tile0 + it;
        const int ty = (tidx >> 5) * 8;
        const int tx = (tidx & 31) * 16;
        const int gx = tx + lr;

        // issue next tile's staging (hidden under compute)
        if (it < 15) stage_b(lds, xpb, p ^ 1, tidx + 1, w, lane);

        // issue noise loads early (waited at use in epilogue)
        float nv[2];
        int gyv[2];
        #pragma unroll
        for (int i = 0; i < 2; ++i) {
            gyv[i] = ty + 2 * w + i;
            nv[i] = nz[gyv[i] * WW + gx];
        }

        // ---- compute from buf p: LDS-only inner loop ----
        const ushort* bufp = &lds[A_U + p * B_STR];
        f32x4 acc[4][2];
        #pragma unroll
        for (int m = 0; m < 4; ++m)
            #pragma unroll
            for (int i = 0; i < 2; ++i) acc[m][i] = (f32x4){0.f, 0.f, 0.f, 0.f};

        #pragma unroll
        for (int dy = 0; dy < 3; ++dy) {
            #pragma unroll
            for (int dx = 0; dx < 3; ++dx) {
                #pragma unroll
                for (int kb = 0; kb < 2; ++kb) {
                    const int off = dy * 3 + dx;
                    bf16x8 afr[4], bfr[2];
                    #pragma unroll
                    for (int m = 0; m < 4; ++m)
                        afr[m] = *(const bf16x8*)&lds[aidx[m][kb] + off * 64];
                    #pragma unroll
                    for (int i = 0; i < 2; ++i) {
                        int idx = (bidx[i][dx] + dy * (18 * 64)) ^ (kb << 5);
                        bfr[i] = *(const bf16x8*)&bufp[idx];
                    }
                    #pragma unroll
                    for (int m = 0; m < 4; ++m)
                        #pragma unroll
                        for (int i = 0; i < 2; ++i)
                            acc[m][i] = __builtin_amdgcn_mfma_f32_16x16x32_bf16(
                                afr[m], bfr[i], acc[m][i], 0, 0, 0);
                }
            }
        }

        // next-tile loads had the whole compute to land; drain + swap
        asm volatile("s_waitcnt vmcnt(0)" ::: "memory");
        __syncthreads();

        // ---- epilogue: +noise, +bias, lrelu*sqrt2, clamp, store ----
        #pragma unroll
        for (int m = 0; m < 4; ++m) {
            #pragma unroll
            for (int i = 0; i < 2; ++i) {
                #pragma unroll
                for (int rg2 = 0; rg2 < 4; ++rg2) {
                    int co = m * 16 + lq * 4 + rg2;
                    float y = acc[m][i][rg2] + nv[i] + bv[m][rg2];
                    y = (y >= 0.f ? y : 0.2f * y) * 1.41421356237f;
                    y = fminf(fmaxf(y, -256.f), 256.f);
                    out[((size_t)(b * 64 + co) * HH + gyv[i]) * WW + gx] = y;
                }
            }
        }
        p ^= 1;
    }
}

extern "C" void kernel_launch(void* const* d_in, const int* in_sizes, int n_in,
                              void* d_out, int out_size, void* d_ws, size_t ws_size,
                              hipStream_t stream) {
    const float* x     = (const float*)d_in[0];
    const float* wsv   = (const float*)d_in[1];
    const float* noise = (const float*)d_in[2];
    const float* aw    = (const float*)d_in[3];
    const float* ab    = (const float*)d_in[4];
    const float* cw    = (const float*)d_in[5];
    const float* bias  = (const float*)d_in[6];
    float* out = (float*)d_out;

    float*  styles = (float*)d_ws;                          // 1 KB
    ushort* wb16   = (ushort*)((char*)d_ws + 1024);         // 294912 B
    ushort* xpad   = (ushort*)((char*)d_ws + (1 << 20));    // 135.3 MB

    hipFuncSetAttribute((const void*)k_conv,
                        hipFuncAttributeMaxDynamicSharedMemorySize, LDS_BYTES);

    k_styles<<<256, 64, 0, stream>>>(wsv, aw, ab, styles);
    k_wmod<<<256, 64, 0, stream>>>(cw, styles, wb16);
    k_zeropad<<<33, 256, 0, stream>>>(xpad);
    k_xpose<<<8192, 256, 0, stream>>>(x, xpad);
    k_conv<<<512, 256, LDS_BYTES, stream>>>(xpad, wb16, noise, bias, out);
}

// Round 10
// 253.539 us; speedup vs baseline: 1.6087x; 1.0549x over previous
//
#include <hip/hip_runtime.h>
#include <math.h>

#define HH 512
#define WW 512
#define HW (HH * WW)
#define PW 514                    // padded width/height
#define PPIX (PW * PW)

#define A_U 36864                 // 64co*9off*64ci ushorts = 73728 B
#define B_U 11776                 // 23*512 ushorts = 23552 B per B buffer
#define LDS_BYTES ((A_U + 2 * B_U) * 2)   // 120832 B <= 128KB (HK-proven range)

typedef short bf16x8 __attribute__((ext_vector_type(8)));
typedef float f32x4 __attribute__((ext_vector_type(4)));

__device__ __forceinline__ ushort f2bf(float f) {
    union { float f; uint u; } c; c.f = f;
    uint u = c.u;
    return (ushort)((u + 0x7fffu + ((u >> 16) & 1u)) >> 16);
}

__device__ __forceinline__ uint cvtpk(float a, float b) {
    uint r;
    asm("v_cvt_pk_bf16_f32 %0, %1, %2" : "=v"(r) : "v"(a), "v"(b));
    return r;
}

// ---------------- kernel 1: styles ----------------
__global__ void k_styles(const float* __restrict__ wsv, const float* __restrict__ aw,
                         const float* __restrict__ ab, float* __restrict__ styles) {
    int bid = blockIdx.x;
    int b = bid >> 6, ci = bid & 63;
    int l = threadIdx.x;
    const float* wrow = wsv + b * 512;
    const float* arow = aw + ci * 512;
    float s = 0.f;
    #pragma unroll
    for (int j = 0; j < 8; ++j)
        s += wrow[l + 64 * j] * arow[l + 64 * j];
    #pragma unroll
    for (int off = 32; off; off >>= 1)
        s += __shfl_xor(s, off, 64);
    if (l == 0)
        styles[b * 64 + ci] = s * 0.044194173824159216f + ab[ci];
}

// ------------- kernel 2: modulate+demodulate -> bf16 [b][co][off 9][ci 64] -------------
// ci-group (ci>>3) stored XORed with (co&7): conflict-free A ds_reads after a
// purely LINEAR global_load_lds stage (swizzle baked at write time). (R8-proven)
__global__ void k_wmod(const float* __restrict__ cw, const float* __restrict__ styles,
                       ushort* __restrict__ wb) {
    int b = blockIdx.x >> 6, co = blockIdx.x & 63;
    int ci = threadIdx.x;
    float st = styles[b * 64 + ci];
    const float* wp = cw + (co * 64 + ci) * 9;
    float wv[9];
    float ss = 0.f;
    #pragma unroll
    for (int k = 0; k < 9; ++k) { wv[k] = wp[k] * st; ss += wv[k] * wv[k]; }
    #pragma unroll
    for (int off = 32; off; off >>= 1)
        ss += __shfl_xor(ss, off, 64);
    float dm = 1.0f / sqrtf(ss + 1e-8f);
    int cisw = ((((ci >> 3) ^ co) & 7) << 3) | (ci & 7);
    #pragma unroll
    for (int k = 0; k < 9; ++k)
        wb[((size_t)(b * 64 + co) * 9 + k) * 64 + cisw] = f2bf(wv[k] * dm);
}

// ------------- kernel 2c: x fp32 NCHW -> xp bf16 [b][gy+1][gx+1][ci], pad fused -------------
__global__ __launch_bounds__(256) void k_xpose(
    const float* __restrict__ x, ushort* __restrict__ xp) {
    const int t = threadIdx.x;
    const int bid = blockIdx.x;

    if (bid >= 8192) {            // ---- fused zeropad of the border ----
        int id = (bid - 8192) * 256 + t;
        if (id >= 4 * 2052) return;
        int b = id / 2052, r = id % 2052;
        int gyp, gxp;
        if (r < 514)       { gyp = 0;        gxp = r; }
        else if (r < 1028) { gyp = 513;      gxp = r - 514; }
        else if (r < 1540) { gyp = r - 1027; gxp = 0; }
        else               { gyp = r - 1539; gxp = 513; }
        ushort* p = xp + (((size_t)b * PW + gyp) * PW + gxp) * 64;
        uint4 z = make_uint4(0, 0, 0, 0);
        #pragma unroll
        for (int i = 0; i < 8; ++i) *(uint4*)(p + i * 8) = z;
        return;
    }

    __shared__ ushort lt[128 * 68];
    const int gxt = bid & 3;
    const int gy  = (bid >> 2) & 511;
    const int b   = bid >> 11;

    const float* xb = x + (size_t)b * 64 * HW + (size_t)gy * WW + gxt * 128;
    const int ci0 = 8 * (t >> 5);
    const int gxc = t & 31;

    f32x4 v[8];
    #pragma unroll
    for (int j = 0; j < 8; ++j)
        v[j] = *(const f32x4*)(xb + (size_t)(ci0 + j) * HW + gxc * 4);

    #pragma unroll
    for (int p = 0; p < 4; ++p) {
        int px = gxc * 4 + p;
        int rowp = ((px & 3) * 32 + (px >> 2)) * 68;
        #pragma unroll
        for (int cg = 0; cg < 2; ++cg) {
            uint lo = cvtpk(v[4 * cg + 0][p], v[4 * cg + 1][p]);
            uint hi = cvtpk(v[4 * cg + 2][p], v[4 * cg + 3][p]);
            *(uint2*)&lt[rowp + ci0 + 4 * cg] = make_uint2(lo, hi);
        }
    }
    __syncthreads();

    const int px = t >> 1, half = t & 1;
    const int rowp = ((px & 3) * 32 + (px >> 2)) * 68 + half * 32;
    uint4 o0 = *(uint4*)&lt[rowp + 0];
    uint4 o1 = *(uint4*)&lt[rowp + 8];
    uint4 o2 = *(uint4*)&lt[rowp + 16];
    uint4 o3 = *(uint4*)&lt[rowp + 24];
    ushort* dst = xp + (((size_t)b * PW + (gy + 1)) * PW + (gxt * 128 + px + 1)) * 64
                     + half * 32;
    *(uint4*)(dst + 0)  = o0;
    *(uint4*)(dst + 8)  = o1;
    *(uint4*)(dst + 16) = o2;
    *(uint4*)(dst + 24) = o3;
}

// ---- stage one B x-tile (10 rows x 18 cols x 64 ci) into buffer p (R8-proven) ----
__device__ __forceinline__ void stage_b(ushort* lds, const ushort* __restrict__ xpb,
                                        int p, int band, int ct, int w, int lane) {
    const int ty = band * 8;
    const int tx = ct * 16;
    for (int j = w; j < 23; j += 8) {
        int c = j * 64 + lane;
        int c2 = c < 1439 ? c : 1439;       // tail clamp; dst overflow lands in pad
        int cig = c2 & 7;
        int pxl = c2 >> 3;
        int row = pxl / 18;
        int lcol = pxl - row * 18;
        int gsrc = cig ^ (lcol & 7);        // pre-swizzled source ci-group
        const ushort* src = xpb + ((size_t)(ty + row) * PW + (tx + lcol)) * 64 + gsrc * 8;
        __builtin_amdgcn_global_load_lds(
            (const __attribute__((address_space(1))) unsigned int*)src,
            (__attribute__((address_space(3))) unsigned int*)&lds[A_U + p * B_U + j * 512],
            16, 0, 0);
    }
}

// ------------- kernel 3: persistent 8-wave MFMA conv, A-in-LDS, B double-buffered -------------
// 256 blocks (1/CU), 512 threads (8 waves = 2/SIMD). Block = (b, band of 8 rows).
// A (64co x 576 = 72KB) staged once; 32 col-tiles (8x16 px) pipelined:
//   issue gload_lds(B next) -> compute cur -> vmcnt(0)+barrier -> store cur.
// Wave grid 2m x 4n; each wave 2 m-frags x 2 n-frags (4 MFMA / 4 ds_read per phase).
__global__ __launch_bounds__(512) void k_conv(
    const ushort* __restrict__ xp,    // [4][514][514][64] bf16 padded
    const ushort* __restrict__ wb,    // [4][64co][9][64ci] bf16 (swizzle baked)
    const float* __restrict__ noise,  // [4][1][512][512]
    const float* __restrict__ bias,   // [64]
    float* __restrict__ out) {        // [4][64][512][512] fp32
    extern __shared__ __align__(16) ushort lds[];

    const int t = threadIdx.x;
    const int w = t >> 6;
    const int lane = t & 63;
    const int blk = blockIdx.x;
    const int b = blk >> 6;
    const int band = blk & 63;

    const ushort* xpb = xp + (size_t)b * PPIX * 64;
    const ushort* wA  = wb + (size_t)b * 64 * 576;

    // ---- stage A once: 72 x 1KB linear copy ----
    for (int j = w; j < 72; j += 8) {
        const ushort* src = wA + j * 512 + lane * 8;
        __builtin_amdgcn_global_load_lds(
            (const __attribute__((address_space(1))) unsigned int*)src,
            (__attribute__((address_space(3))) unsigned int*)&lds[j * 512],
            16, 0, 0);
    }
    stage_b(lds, xpb, 0, band, 0, w, lane);
    asm volatile("s_waitcnt vmcnt(0)" ::: "memory");
    __syncthreads();

    const int lr = lane & 15;
    const int lq = lane >> 4;
    const int wm = w >> 2;               // 0..1 -> m-half (co 0..31 / 32..63)
    const int wn = w & 3;                // 0..3 -> row-pair (rows 2wn, 2wn+1)

    // A read offsets (R8-proven formula, 0 conflicts): [co][off][ci-swizzled]
    int aidx[2][2];
    #pragma unroll
    for (int m = 0; m < 2; ++m)
        #pragma unroll
        for (int kb = 0; kb < 2; ++kb)
            aidx[m][kb] = ((2 * wm + m) * 16 + lr) * 576 + ((((kb << 2) | lq) ^ (lr & 7)) << 3);

    // B read offsets (R8-proven): row = 2wn+i, [row][lcol][ci-swizzled]
    int bidx[2][3];
    #pragma unroll
    for (int i = 0; i < 2; ++i)
        #pragma unroll
        for (int dx = 0; dx < 3; ++dx) {
            int lcol = lr + dx;
            bidx[i][dx] = ((2 * wn + i) * 18 + lcol) * 64 + ((lq * 8) ^ ((lcol & 7) << 3));
        }

    f32x4 bv[2];
    #pragma unroll
    for (int m = 0; m < 2; ++m)
        bv[m] = *(const f32x4*)&bias[(2 * wm + m) * 16 + lq * 4];
    const float* nz = noise + (size_t)b * HW;
    const int ty = band * 8;

    int p = 0;
    for (int it = 0; it < 32; ++it) {
        const int tx = it * 16;
        const int gx = tx + lr;

        // issue next tile's staging (hidden under compute)
        if (it < 31) stage_b(lds, xpb, p ^ 1, band, it + 1, w, lane);

        // noise loads (waited at epilogue)
        float nv[2];
        int gyv[2];
        #pragma unroll
        for (int i = 0; i < 2; ++i) {
            gyv[i] = ty + 2 * wn + i;
            nv[i] = nz[gyv[i] * WW + gx];
        }

        // ---- compute from buf p: LDS-only inner loop ----
        const ushort* bufp = &lds[A_U + p * B_U];
        f32x4 acc[2][2];
        #pragma unroll
        for (int m = 0; m < 2; ++m)
            #pragma unroll
            for (int i = 0; i < 2; ++i) acc[m][i] = (f32x4){0.f, 0.f, 0.f, 0.f};

        #pragma unroll
        for (int dy = 0; dy < 3; ++dy) {
            #pragma unroll
            for (int dx = 0; dx < 3; ++dx) {
                #pragma unroll
                for (int kb = 0; kb < 2; ++kb) {
                    const int off = dy * 3 + dx;
                    bf16x8 afr[2], bfr[2];
                    #pragma unroll
                    for (int m = 0; m < 2; ++m)
                        afr[m] = *(const bf16x8*)&lds[aidx[m][kb] + off * 64];
                    #pragma unroll
                    for (int i = 0; i < 2; ++i) {
                        int idx = (bidx[i][dx] + dy * (18 * 64)) ^ (kb << 5);
                        bfr[i] = *(const bf16x8*)&bufp[idx];
                    }
                    #pragma unroll
                    for (int m = 0; m < 2; ++m)
                        #pragma unroll
                        for (int i = 0; i < 2; ++i)
                            acc[m][i] = __builtin_amdgcn_mfma_f32_16x16x32_bf16(
                                afr[m], bfr[i], acc[m][i], 0, 0, 0);
                }
            }
        }

        // next-tile loads + noise had the whole compute to land; drain + swap
        asm volatile("s_waitcnt vmcnt(0)" ::: "memory");
        __syncthreads();

        // ---- epilogue: +noise, +bias, lrelu*sqrt2, clamp, store ----
        #pragma unroll
        for (int m = 0; m < 2; ++m) {
            #pragma unroll
            for (int i = 0; i < 2; ++i) {
                #pragma unroll
                for (int rg2 = 0; rg2 < 4; ++rg2) {
                    int co = (2 * wm + m) * 16 + lq * 4 + rg2;
                    float y = acc[m][i][rg2] + nv[i] + bv[m][rg2];
                    y = (y >= 0.f ? y : 0.2f * y) * 1.41421356237f;
                    y = fminf(fmaxf(y, -256.f), 256.f);
                    out[((size_t)(b * 64 + co) * HH + gyv[i]) * WW + gx] = y;
                }
            }
        }
        p ^= 1;
    }
}

extern "C" void kernel_launch(void* const* d_in, const int* in_sizes, int n_in,
                              void* d_out, int out_size, void* d_ws, size_t ws_size,
                              hipStream_t stream) {
    const float* x     = (const float*)d_in[0];
    const float* wsv   = (const float*)d_in[1];
    const float* noise = (const float*)d_in[2];
    const float* aw    = (const float*)d_in[3];
    const float* ab    = (const float*)d_in[4];
    const float* cw    = (const float*)d_in[5];
    const float* bias  = (const float*)d_in[6];
    float* out = (float*)d_out;

    float*  styles = (float*)d_ws;                          // 1 KB
    ushort* wb16   = (ushort*)((char*)d_ws + 1024);         // 294912 B
    ushort* xpad   = (ushort*)((char*)d_ws + (1 << 20));    // 135.3 MB

    hipFuncSetAttribute((const void*)k_conv,
                        hipFuncAttributeMaxDynamicSharedMemorySize, LDS_BYTES);

    k_styles<<<256, 64, 0, stream>>>(wsv, aw, ab, styles);
    k_wmod<<<256, 64, 0, stream>>>(cw, styles, wb16);
    k_xpose<<<8225, 256, 0, stream>>>(x, xpad);
    k_conv<<<256, 512, LDS_BYTES, stream>>>(xpad, wb16, noise, bias, out);
}